// Round 9
// baseline (179.730 us; speedup 1.0000x reference)
//
#include <hip/hip_runtime.h>

// ===== MEASUREMENT ROUND: code identical to R8; mv_fuse_kernel launched
// ===== twice (idempotent) so T9 - T8 = fuse duration exactly. =====

#define NV 12
#define CIN 384
#define COUT 32
#define HW 4096        // 64*64 feature pixels
#define NVOX 262144    // 64^3 voxels
#define KSTEPS 12      // 384 / 32
#define KSTEP 32
#define KPAD 33        // +1 pad: ds bank rotation
#define PIXB 128       // pixels per block (4 waves x 2 x 16)
#define ZROW_U4 786432 // uint4 index of the 64B zero row (= 48*4096*32 bf16 / 8)

typedef __attribute__((ext_vector_type(8))) short short8v;   // 8 bf16 (4 VGPR)
typedef __attribute__((ext_vector_type(4))) short short4v;   // 4 bf16 (2 VGPR)
typedef __attribute__((ext_vector_type(4))) float f32x4;     // MFMA accum

// fp32 -> bf16 bits, round-to-nearest-even (finite data; NaN not handled).
__device__ __forceinline__ short bf16b(float x) {
    union { float f; unsigned u; } c; c.f = x;
    unsigned r = (c.u + 0x7fffu + ((c.u >> 16) & 1u)) >> 16;
    return (short)r;
}

// Prep: repack W into MFMA A-fragment order (bf16) + zero the fuse zero-row.
__global__ __launch_bounds__(256) void w_prep_kernel(
    const float* __restrict__ w, short* __restrict__ wfrag,
    short* __restrict__ feats)
{
    const int t = blockIdx.x * 256 + threadIdx.x;
    if (t < 48 * 32) {
        const int sg = t >> 5, o = t & 31;
        const int s = sg >> 2, g = sg & 3;
        short8v v;
#pragma unroll
        for (int i = 0; i < 8; ++i)
            v[i] = bf16b(w[o * CIN + s * 32 + g * 8 + i]);
        *reinterpret_cast<short8v*>(wfrag + t * 8) = v;
    } else if (t >= 1536 && t < 1540) {
        reinterpret_cast<uint4*>(feats)[ZROW_U4 + (t - 1536)] =
            make_uint4(0u, 0u, 0u, 0u);
    }
}

// Kernel 1: channel reduce 384->32 on matrix cores, LDS-staged, 128-pix tile.
// (Unchanged from R7/R8.)
__global__ __launch_bounds__(256) void mv_reduce_mfma_kernel(
    const float* __restrict__ vit, const short* __restrict__ wfrag,
    const float* __restrict__ bias, short* __restrict__ feats)
{
    __shared__ float lds[PIXB][KPAD];        // 16896 B

    const int bid  = blockIdx.x;             // 0..1535
    const int bv   = bid >> 5;               // 0..47
    const int pix0 = (bid & 31) * PIXB;

    const int tid  = threadIdx.x;
    const int wave = tid >> 6;               // 0..3
    const int l    = tid & 63;
    const int col  = l & 15;                 // pixel-in-tile / o-in-tile
    const int g    = l >> 4;                 // k-group

    const int kk  = tid >> 4;                // staging k-row 0..15
    const int px4 = (tid & 15) * 4;          // staging pixel quad 0..60

    const float* vbase = vit + (size_t)bv * CIN * HW + pix0;
    const short8v* wf  = reinterpret_cast<const short8v*>(wfrag);

    f32x4 acc00 = {0.f, 0.f, 0.f, 0.f};
    f32x4 acc01 = {0.f, 0.f, 0.f, 0.f};
    f32x4 acc10 = {0.f, 0.f, 0.f, 0.f};
    f32x4 acc11 = {0.f, 0.f, 0.f, 0.f};

#pragma unroll
    for (int s = 0; s < KSTEPS; ++s) {
        const float* r0base = vbase + (size_t)(s * KSTEP + kk) * HW;
        const float* r1base = vbase + (size_t)(s * KSTEP + kk + 16) * HW;
        const float4 r00 = *reinterpret_cast<const float4*>(r0base + px4);
        const float4 r01 = *reinterpret_cast<const float4*>(r0base + px4 + 64);
        const float4 r10 = *reinterpret_cast<const float4*>(r1base + px4);
        const float4 r11 = *reinterpret_cast<const float4*>(r1base + px4 + 64);

        __syncthreads();
        lds[px4 + 0][kk] = r00.x;  lds[px4 + 1][kk] = r00.y;
        lds[px4 + 2][kk] = r00.z;  lds[px4 + 3][kk] = r00.w;
        lds[px4 + 64][kk] = r01.x; lds[px4 + 65][kk] = r01.y;
        lds[px4 + 66][kk] = r01.z; lds[px4 + 67][kk] = r01.w;
        lds[px4 + 0][kk + 16] = r10.x;  lds[px4 + 1][kk + 16] = r10.y;
        lds[px4 + 2][kk + 16] = r10.z;  lds[px4 + 3][kk + 16] = r10.w;
        lds[px4 + 64][kk + 16] = r11.x; lds[px4 + 65][kk + 16] = r11.y;
        lds[px4 + 66][kk + 16] = r11.z; lds[px4 + 67][kk + 16] = r11.w;
        __syncthreads();

        const float4 f0a = *reinterpret_cast<const float4*>(&lds[wave * 32 + col][8 * g]);
        const float4 f0b = *reinterpret_cast<const float4*>(&lds[wave * 32 + col][8 * g + 4]);
        const float4 f1a = *reinterpret_cast<const float4*>(&lds[wave * 32 + 16 + col][8 * g]);
        const float4 f1b = *reinterpret_cast<const float4*>(&lds[wave * 32 + 16 + col][8 * g + 4]);

        short8v bfr0, bfr1;
        bfr0[0] = bf16b(f0a.x); bfr0[1] = bf16b(f0a.y);
        bfr0[2] = bf16b(f0a.z); bfr0[3] = bf16b(f0a.w);
        bfr0[4] = bf16b(f0b.x); bfr0[5] = bf16b(f0b.y);
        bfr0[6] = bf16b(f0b.z); bfr0[7] = bf16b(f0b.w);
        bfr1[0] = bf16b(f1a.x); bfr1[1] = bf16b(f1a.y);
        bfr1[2] = bf16b(f1a.z); bfr1[3] = bf16b(f1a.w);
        bfr1[4] = bf16b(f1b.x); bfr1[5] = bf16b(f1b.y);
        bfr1[6] = bf16b(f1b.z); bfr1[7] = bf16b(f1b.w);

        const short8v a0 = wf[(s * 4 + g) * 32 + col];
        const short8v a1 = wf[(s * 4 + g) * 32 + 16 + col];

        acc00 = __builtin_amdgcn_mfma_f32_16x16x32_bf16(a0, bfr0, acc00, 0, 0, 0);
        acc01 = __builtin_amdgcn_mfma_f32_16x16x32_bf16(a1, bfr0, acc01, 0, 0, 0);
        acc10 = __builtin_amdgcn_mfma_f32_16x16x32_bf16(a0, bfr1, acc10, 0, 0, 0);
        acc11 = __builtin_amdgcn_mfma_f32_16x16x32_bf16(a1, bfr1, acc11, 0, 0, 0);
    }

    const float4 b0 = *reinterpret_cast<const float4*>(bias + 4 * g);
    const float4 b1 = *reinterpret_cast<const float4*>(bias + 16 + 4 * g);
    short* dst0 = feats + ((size_t)bv * HW + pix0 + wave * 32 + col) * COUT;
    short* dst1 = dst0 + 16 * COUT;
    short4v o00, o01, o10, o11;
    o00[0] = bf16b(acc00[0] + b0.x); o00[1] = bf16b(acc00[1] + b0.y);
    o00[2] = bf16b(acc00[2] + b0.z); o00[3] = bf16b(acc00[3] + b0.w);
    o01[0] = bf16b(acc01[0] + b1.x); o01[1] = bf16b(acc01[1] + b1.y);
    o01[2] = bf16b(acc01[2] + b1.z); o01[3] = bf16b(acc01[3] + b1.w);
    o10[0] = bf16b(acc10[0] + b0.x); o10[1] = bf16b(acc10[1] + b0.y);
    o10[2] = bf16b(acc10[2] + b0.z); o10[3] = bf16b(acc10[3] + b0.w);
    o11[0] = bf16b(acc11[0] + b1.x); o11[1] = bf16b(acc11[1] + b1.y);
    o11[2] = bf16b(acc11[2] + b1.z); o11[3] = bf16b(acc11[3] + b1.w);
    *reinterpret_cast<short4v*>(dst0 + 4 * g) = o00;
    *reinterpret_cast<short4v*>(dst0 + 16 + 4 * g) = o01;
    *reinterpret_cast<short4v*>(dst1 + 4 * g) = o10;
    *reinterpret_cast<short4v*>(dst1 + 16 + 4 * g) = o11;
}

// Kernel 2: fuse, 4 lanes per voxel (R8 form, unchanged).
__global__ __launch_bounds__(256) void mv_fuse_kernel(
    const unsigned short* __restrict__ feats, const float* __restrict__ proj,
    float* __restrict__ out)
{
    __shared__ double P[NV][12];

    const int tid = threadIdx.x;
    const unsigned gid = blockIdx.x * 256u + tid;
    const unsigned vox = gid >> 2;          // voxel id = b*NVOX + n
    const int r = tid & 3;                  // chunk index within group
    const int lane = tid & 63;
    const int b = vox >> 18;
    const int n = vox & (NVOX - 1);

    if (tid < NV * 12) {
        const int v = tid / 12, e = tid - v * 12;
        const int row = e >> 2;
        const float s = (row < 2) ? 0.25f : 1.0f;   // projection[:,:, :2,:]/STRIDE
        P[v][e] = (double)(proj[((b * NV + v) * 3 + row) * 4 + (e & 3)] * s);
    }
    __syncthreads();

    const int k = n & 63, j = (n >> 6) & 63, i = n >> 12;
    const double wx = (double)i * 0.04 - 1.28;
    const double wy = (double)j * 0.04 - 1.28;
    const double wz = (double)k * 0.04 - 1.28;

    // Phase 1: this lane's 3 views (v = 4s + r).
    int off[3];
    int cnt = 0;
    const int bbase = b * (NV * HW * 4);
#pragma unroll
    for (int s = 0; s < 3; ++s) {
        const double* p = P[4 * s + r];
        const double cz = p[8] * wx + p[9] * wy + p[10] * wz + p[11];
        const double cx = p[0] * wx + p[1] * wy + p[2] * wz + p[3];
        const double cy = p[4] * wx + p[5] * wy + p[6] * wz + p[7];
        const double u = rint(cx / cz);   // round-half-even == jnp.round
        const double t = rint(cy / cz);
        const bool valid = (cz > 0.0) & (u >= 0.0) & (u <= 63.0) &
                           (t >= 0.0) & (t <= 63.0);
        const double uc = fmin(fmax(u, 0.0), 63.0);
        const double tc = fmin(fmax(t, 0.0), 63.0);
        const int pix = (int)uc + 64 * (int)tc;
        off[s] = valid ? (bbase + ((4 * s + r) * HW + pix) * 4) : ZROW_U4;
        cnt += valid ? 1 : 0;
    }
    cnt += __shfl_xor(cnt, 1);
    cnt += __shfl_xor(cnt, 2);              // group-total valid count

    // Phase 2: gather + accumulate (channels 8r..8r+7 in this lane).
    float acc[8];
#pragma unroll
    for (int q = 0; q < 8; ++q) acc[q] = 0.0f;

    const uint4* f4 = reinterpret_cast<const uint4*>(feats);
#pragma unroll
    for (int v = 0; v < NV; ++v) {
        const int src = (lane & ~3) | (v & 3);      // owner lane of view v
        const int ov = __shfl(off[v >> 2], src, 64);
        const uint4 u4 = f4[ov + r];
        acc[0] += __uint_as_float(u4.x << 16);
        acc[1] += __uint_as_float(u4.x & 0xffff0000u);
        acc[2] += __uint_as_float(u4.y << 16);
        acc[3] += __uint_as_float(u4.y & 0xffff0000u);
        acc[4] += __uint_as_float(u4.z << 16);
        acc[5] += __uint_as_float(u4.z & 0xffff0000u);
        acc[6] += __uint_as_float(u4.w << 16);
        acc[7] += __uint_as_float(u4.w & 0xffff0000u);
    }

    const float sc = (cnt > 0) ? (1.0f / (float)cnt) : 0.0f;
    float* ob = out + (size_t)b * COUT * NVOX + (size_t)(8 * r) * NVOX + n;
#pragma unroll
    for (int q = 0; q < 8; ++q)
        ob[(size_t)q * NVOX] = acc[q] * sc;
}

extern "C" void kernel_launch(void* const* d_in, const int* in_sizes, int n_in,
                              void* d_out, int out_size, void* d_ws, size_t ws_size,
                              hipStream_t stream) {
    const float* vit  = (const float*)d_in[0];  // (4,12,384,64,64)
    const float* w    = (const float*)d_in[1];  // (32,384)
    const float* bias = (const float*)d_in[2];  // (32,)
    const float* proj = (const float*)d_in[3];  // (4,12,3,4)
    float* out = (float*)d_out;                 // (4,32,64,64,64)

    short* wfrag = (short*)d_ws;                            // 24 KB
    short* feats = (short*)((char*)d_ws + 48 * 32 * 8 * 2); // bf16 12.6 MB + 64B zero row

    w_prep_kernel<<<7, 256, 0, stream>>>(w, wfrag, feats);

    mv_reduce_mfma_kernel<<<1536, 256, 0, stream>>>(vit, wfrag, bias, feats);

    // Launched TWICE (idempotent): T9 - T8 isolates the fuse duration.
    mv_fuse_kernel<<<16384, 256, 0, stream>>>(
        (const unsigned short*)feats, proj, out);
    mv_fuse_kernel<<<16384, 256, 0, stream>>>(
        (const unsigned short*)feats, proj, out);
}

// Round 10
// 128.047 us; speedup vs baseline: 1.4036x; 1.4036x over previous
//
#include <hip/hip_runtime.h>

#define NV 12
#define CIN 384
#define COUT 32
#define HW 4096        // 64*64 feature pixels
#define NVOX 262144    // 64^3 voxels
#define KSTEPS 12      // 384 / 32
#define KSTEP 32
#define KPAD 33        // +1 pad: ds bank rotation
#define PIXB 128       // pixels per block (4 waves x 2 x 16)
#define ZROW_U4 786432 // uint4 index of the 64B zero row (= 48*4096*32 bf16 / 8)

typedef __attribute__((ext_vector_type(8))) short short8v;   // 8 bf16 (4 VGPR)
typedef __attribute__((ext_vector_type(4))) short short4v;   // 4 bf16 (2 VGPR)
typedef __attribute__((ext_vector_type(4))) float f32x4;     // MFMA accum

// fp32 -> bf16 bits, round-to-nearest-even (finite data; NaN not handled).
__device__ __forceinline__ short bf16b(float x) {
    union { float f; unsigned u; } c; c.f = x;
    unsigned r = (c.u + 0x7fffu + ((c.u >> 16) & 1u)) >> 16;
    return (short)r;
}

// Prep: repack W into MFMA A-fragment order (bf16) + zero the fuse zero-row.
__global__ __launch_bounds__(256) void w_prep_kernel(
    const float* __restrict__ w, short* __restrict__ wfrag,
    short* __restrict__ feats)
{
    const int t = blockIdx.x * 256 + threadIdx.x;
    if (t < 48 * 32) {
        const int sg = t >> 5, o = t & 31;
        const int s = sg >> 2, g = sg & 3;
        short8v v;
#pragma unroll
        for (int i = 0; i < 8; ++i)
            v[i] = bf16b(w[o * CIN + s * 32 + g * 8 + i]);
        *reinterpret_cast<short8v*>(wfrag + t * 8) = v;
    } else if (t >= 1536 && t < 1540) {
        reinterpret_cast<uint4*>(feats)[ZROW_U4 + (t - 1536)] =
            make_uint4(0u, 0u, 0u, 0u);
    }
}

// Kernel 1: channel reduce 384->32, MFMA, LDS-staged, 128-pix tile.
// R10 change (T14): loop rotated so next-step global loads are ISSUED BEFORE
// the compute phase. The compiler's mandatory `s_waitcnt vmcnt(0)` before
// each s_barrier then drains loads that have had a full compute phase
// (~300+ cyc x 6 waves/SIMD) in flight, instead of freshly-issued ones
// (R7 order exposed full HBM latency at every barrier, 12x/block).
__global__ __launch_bounds__(256) void mv_reduce_mfma_kernel(
    const float* __restrict__ vit, const short* __restrict__ wfrag,
    const float* __restrict__ bias, short* __restrict__ feats)
{
    __shared__ float lds[PIXB][KPAD];        // 16896 B -> 6 blocks/CU

    const int bid  = blockIdx.x;             // 0..1535
    const int bv   = bid >> 5;               // 0..47
    const int pix0 = (bid & 31) * PIXB;

    const int tid  = threadIdx.x;
    const int wave = tid >> 6;               // 0..3
    const int l    = tid & 63;
    const int col  = l & 15;                 // pixel-in-tile / o-in-tile
    const int g    = l >> 4;                 // k-group

    const int kk  = tid >> 4;                // staging k-row 0..15
    const int px4 = (tid & 15) * 4;          // staging pixel quad 0..60

    const float* vbase = vit + (size_t)bv * CIN * HW + pix0;
    const short8v* wf  = reinterpret_cast<const short8v*>(wfrag);

    f32x4 acc00 = {0.f, 0.f, 0.f, 0.f};
    f32x4 acc01 = {0.f, 0.f, 0.f, 0.f};
    f32x4 acc10 = {0.f, 0.f, 0.f, 0.f};
    f32x4 acc11 = {0.f, 0.f, 0.f, 0.f};

    // Prologue: stage step 0 into registers.
    float4 r00, r01, r10, r11;
    {
        const float* r0base = vbase + (size_t)kk * HW;
        const float* r1base = vbase + (size_t)(kk + 16) * HW;
        r00 = *reinterpret_cast<const float4*>(r0base + px4);
        r01 = *reinterpret_cast<const float4*>(r0base + px4 + 64);
        r10 = *reinterpret_cast<const float4*>(r1base + px4);
        r11 = *reinterpret_cast<const float4*>(r1base + px4 + 64);
    }

#pragma unroll
    for (int s = 0; s < KSTEPS; ++s) {
        __syncthreads();                     // (a) prior step's LDS reads done
        lds[px4 + 0][kk] = r00.x;  lds[px4 + 1][kk] = r00.y;
        lds[px4 + 2][kk] = r00.z;  lds[px4 + 3][kk] = r00.w;
        lds[px4 + 64][kk] = r01.x; lds[px4 + 65][kk] = r01.y;
        lds[px4 + 66][kk] = r01.z; lds[px4 + 67][kk] = r01.w;
        lds[px4 + 0][kk + 16] = r10.x;  lds[px4 + 1][kk + 16] = r10.y;
        lds[px4 + 2][kk + 16] = r10.z;  lds[px4 + 3][kk + 16] = r10.w;
        lds[px4 + 64][kk + 16] = r11.x; lds[px4 + 65][kk + 16] = r11.y;
        lds[px4 + 66][kk + 16] = r11.z; lds[px4 + 67][kk + 16] = r11.w;
        __syncthreads();                     // (b) writes visible

        // ISSUE next step's loads NOW — they fly during compute below.
        if (s + 1 < KSTEPS) {
            const float* r0base = vbase + (size_t)((s + 1) * KSTEP + kk) * HW;
            const float* r1base = r0base + (size_t)16 * HW;
            r00 = *reinterpret_cast<const float4*>(r0base + px4);
            r01 = *reinterpret_cast<const float4*>(r0base + px4 + 64);
            r10 = *reinterpret_cast<const float4*>(r1base + px4);
            r11 = *reinterpret_cast<const float4*>(r1base + px4 + 64);
        }

        // Compute step s from LDS.
        const float4 f0a = *reinterpret_cast<const float4*>(&lds[wave * 32 + col][8 * g]);
        const float4 f0b = *reinterpret_cast<const float4*>(&lds[wave * 32 + col][8 * g + 4]);
        const float4 f1a = *reinterpret_cast<const float4*>(&lds[wave * 32 + 16 + col][8 * g]);
        const float4 f1b = *reinterpret_cast<const float4*>(&lds[wave * 32 + 16 + col][8 * g + 4]);

        short8v bfr0, bfr1;
        bfr0[0] = bf16b(f0a.x); bfr0[1] = bf16b(f0a.y);
        bfr0[2] = bf16b(f0a.z); bfr0[3] = bf16b(f0a.w);
        bfr0[4] = bf16b(f0b.x); bfr0[5] = bf16b(f0b.y);
        bfr0[6] = bf16b(f0b.z); bfr0[7] = bf16b(f0b.w);
        bfr1[0] = bf16b(f1a.x); bfr1[1] = bf16b(f1a.y);
        bfr1[2] = bf16b(f1a.z); bfr1[3] = bf16b(f1a.w);
        bfr1[4] = bf16b(f1b.x); bfr1[5] = bf16b(f1b.y);
        bfr1[6] = bf16b(f1b.z); bfr1[7] = bf16b(f1b.w);

        const short8v a0 = wf[(s * 4 + g) * 32 + col];
        const short8v a1 = wf[(s * 4 + g) * 32 + 16 + col];

        acc00 = __builtin_amdgcn_mfma_f32_16x16x32_bf16(a0, bfr0, acc00, 0, 0, 0);
        acc01 = __builtin_amdgcn_mfma_f32_16x16x32_bf16(a1, bfr0, acc01, 0, 0, 0);
        acc10 = __builtin_amdgcn_mfma_f32_16x16x32_bf16(a0, bfr1, acc10, 0, 0, 0);
        acc11 = __builtin_amdgcn_mfma_f32_16x16x32_bf16(a1, bfr1, acc11, 0, 0, 0);
    }

    const float4 b0 = *reinterpret_cast<const float4*>(bias + 4 * g);
    const float4 b1 = *reinterpret_cast<const float4*>(bias + 16 + 4 * g);
    short* dst0 = feats + ((size_t)bv * HW + pix0 + wave * 32 + col) * COUT;
    short* dst1 = dst0 + 16 * COUT;
    short4v o00, o01, o10, o11;
    o00[0] = bf16b(acc00[0] + b0.x); o00[1] = bf16b(acc00[1] + b0.y);
    o00[2] = bf16b(acc00[2] + b0.z); o00[3] = bf16b(acc00[3] + b0.w);
    o01[0] = bf16b(acc01[0] + b1.x); o01[1] = bf16b(acc01[1] + b1.y);
    o01[2] = bf16b(acc01[2] + b1.z); o01[3] = bf16b(acc01[3] + b1.w);
    o10[0] = bf16b(acc10[0] + b0.x); o10[1] = bf16b(acc10[1] + b0.y);
    o10[2] = bf16b(acc10[2] + b0.z); o10[3] = bf16b(acc10[3] + b0.w);
    o11[0] = bf16b(acc11[0] + b1.x); o11[1] = bf16b(acc11[1] + b1.y);
    o11[2] = bf16b(acc11[2] + b1.z); o11[3] = bf16b(acc11[3] + b1.w);
    *reinterpret_cast<short4v*>(dst0 + 4 * g) = o00;
    *reinterpret_cast<short4v*>(dst0 + 16 + 4 * g) = o01;
    *reinterpret_cast<short4v*>(dst1 + 4 * g) = o10;
    *reinterpret_cast<short4v*>(dst1 + 16 + 4 * g) = o11;
}

// Kernel 2: fuse, 4 lanes per voxel (R8 form, unchanged; ~48 µs measured).
__global__ __launch_bounds__(256) void mv_fuse_kernel(
    const unsigned short* __restrict__ feats, const float* __restrict__ proj,
    float* __restrict__ out)
{
    __shared__ double P[NV][12];

    const int tid = threadIdx.x;
    const unsigned gid = blockIdx.x * 256u + tid;
    const unsigned vox = gid >> 2;          // voxel id = b*NVOX + n
    const int r = tid & 3;                  // chunk index within group
    const int lane = tid & 63;
    const int b = vox >> 18;
    const int n = vox & (NVOX - 1);

    if (tid < NV * 12) {
        const int v = tid / 12, e = tid - v * 12;
        const int row = e >> 2;
        const float s = (row < 2) ? 0.25f : 1.0f;   // projection[:,:, :2,:]/STRIDE
        P[v][e] = (double)(proj[((b * NV + v) * 3 + row) * 4 + (e & 3)] * s);
    }
    __syncthreads();

    const int k = n & 63, j = (n >> 6) & 63, i = n >> 12;
    const double wx = (double)i * 0.04 - 1.28;
    const double wy = (double)j * 0.04 - 1.28;
    const double wz = (double)k * 0.04 - 1.28;

    // Phase 1: this lane's 3 views (v = 4s + r).
    int off[3];
    int cnt = 0;
    const int bbase = b * (NV * HW * 4);
#pragma unroll
    for (int s = 0; s < 3; ++s) {
        const double* p = P[4 * s + r];
        const double cz = p[8] * wx + p[9] * wy + p[10] * wz + p[11];
        const double cx = p[0] * wx + p[1] * wy + p[2] * wz + p[3];
        const double cy = p[4] * wx + p[5] * wy + p[6] * wz + p[7];
        const double u = rint(cx / cz);   // round-half-even == jnp.round
        const double t = rint(cy / cz);
        const bool valid = (cz > 0.0) & (u >= 0.0) & (u <= 63.0) &
                           (t >= 0.0) & (t <= 63.0);
        const double uc = fmin(fmax(u, 0.0), 63.0);
        const double tc = fmin(fmax(t, 0.0), 63.0);
        const int pix = (int)uc + 64 * (int)tc;
        off[s] = valid ? (bbase + ((4 * s + r) * HW + pix) * 4) : ZROW_U4;
        cnt += valid ? 1 : 0;
    }
    cnt += __shfl_xor(cnt, 1);
    cnt += __shfl_xor(cnt, 2);              // group-total valid count

    // Phase 2: gather + accumulate (channels 8r..8r+7 in this lane).
    float acc[8];
#pragma unroll
    for (int q = 0; q < 8; ++q) acc[q] = 0.0f;

    const uint4* f4 = reinterpret_cast<const uint4*>(feats);
#pragma unroll
    for (int v = 0; v < NV; ++v) {
        const int src = (lane & ~3) | (v & 3);      // owner lane of view v
        const int ov = __shfl(off[v >> 2], src, 64);
        const uint4 u4 = f4[ov + r];
        acc[0] += __uint_as_float(u4.x << 16);
        acc[1] += __uint_as_float(u4.x & 0xffff0000u);
        acc[2] += __uint_as_float(u4.y << 16);
        acc[3] += __uint_as_float(u4.y & 0xffff0000u);
        acc[4] += __uint_as_float(u4.z << 16);
        acc[5] += __uint_as_float(u4.z & 0xffff0000u);
        acc[6] += __uint_as_float(u4.w << 16);
        acc[7] += __uint_as_float(u4.w & 0xffff0000u);
    }

    const float sc = (cnt > 0) ? (1.0f / (float)cnt) : 0.0f;
    float* ob = out + (size_t)b * COUT * NVOX + (size_t)(8 * r) * NVOX + n;
#pragma unroll
    for (int q = 0; q < 8; ++q)
        ob[(size_t)q * NVOX] = acc[q] * sc;
}

extern "C" void kernel_launch(void* const* d_in, const int* in_sizes, int n_in,
                              void* d_out, int out_size, void* d_ws, size_t ws_size,
                              hipStream_t stream) {
    const float* vit  = (const float*)d_in[0];  // (4,12,384,64,64)
    const float* w    = (const float*)d_in[1];  // (32,384)
    const float* bias = (const float*)d_in[2];  // (32,)
    const float* proj = (const float*)d_in[3];  // (4,12,3,4)
    float* out = (float*)d_out;                 // (4,32,64,64,64)

    short* wfrag = (short*)d_ws;                            // 24 KB
    short* feats = (short*)((char*)d_ws + 48 * 32 * 8 * 2); // bf16 12.6 MB + 64B zero row

    w_prep_kernel<<<7, 256, 0, stream>>>(w, wfrag, feats);

    mv_reduce_mfma_kernel<<<1536, 256, 0, stream>>>(vit, wfrag, bias, feats);

    mv_fuse_kernel<<<16384, 256, 0, stream>>>(
        (const unsigned short*)feats, proj, out);
}

// Round 11
// 125.565 us; speedup vs baseline: 1.4314x; 1.0198x over previous
//
#include <hip/hip_runtime.h>

#define NV 12
#define CIN 384
#define COUT 32
#define HW 4096        // 64*64 feature pixels
#define NVOX 262144    // 64^3 voxels
#define KSTEPS 12      // 384 / 32
#define KSTEP 32
#define PIXB 128       // pixels per block (4 waves x 2 x 16)
#define ZROW_U4 786432 // uint4 index of the 64B zero row (= 48*4096*32 bf16 / 8)

typedef __attribute__((ext_vector_type(8))) short short8v;   // 8 bf16 (4 VGPR)
typedef __attribute__((ext_vector_type(4))) short short4v;   // 4 bf16 (2 VGPR)
typedef __attribute__((ext_vector_type(4))) float f32x4;     // MFMA accum

// fp32 -> bf16 bits, round-to-nearest-even (finite data; NaN not handled).
__device__ __forceinline__ short bf16b(float x) {
    union { float f; unsigned u; } c; c.f = x;
    unsigned r = (c.u + 0x7fffu + ((c.u >> 16) & 1u)) >> 16;
    return (short)r;
}

// Async global->LDS DMA, 16B per lane. LDS dest = uniform base + lane*16
// (linear); global src is per-lane.
__device__ __forceinline__ void load_lds16(const float* g, float* l) {
    __builtin_amdgcn_global_load_lds(
        (const __attribute__((address_space(1))) void*)g,
        (__attribute__((address_space(3))) void*)l, 16, 0, 0);
}

// Prep: repack W into MFMA A-fragment order (bf16) + zero the fuse zero-row.
__global__ __launch_bounds__(256) void w_prep_kernel(
    const float* __restrict__ w, short* __restrict__ wfrag,
    short* __restrict__ feats)
{
    const int t = blockIdx.x * 256 + threadIdx.x;
    if (t < 48 * 32) {
        const int sg = t >> 5, o = t & 31;
        const int s = sg >> 2, g = sg & 3;
        short8v v;
#pragma unroll
        for (int i = 0; i < 8; ++i)
            v[i] = bf16b(w[o * CIN + s * 32 + g * 8 + i]);
        *reinterpret_cast<short8v*>(wfrag + t * 8) = v;
    } else if (t >= 1536 && t < 1540) {
        reinterpret_cast<uint4*>(feats)[ZROW_U4 + (t - 1536)] =
            make_uint4(0u, 0u, 0u, 0u);
    }
}

// Kernel 1: channel reduce 384->32, MFMA, global_load_lds-staged.
// LDS is [k][128 pix] f32, DMA-linear. Each wave stages its own 8 k-rows
// (4 insts x 1KB: lanes 0-31 row k, 32-63 row k+1). Row chunks are ROTATED
// by 2*wave chunks at the GLOBAL source (LDS dest must stay linear for DMA),
// so fragment reads lds[8g+i][(pix + 8g) & 127] are 2-way-bank (free) instead
// of the 4-way conflict of the unswizzled [k][pix] layout.
// Removes 16 ds_write_b32 + 16-VGPR staging round-trip per thread per k-step.
__global__ __launch_bounds__(256) void mv_reduce_mfma_kernel(
    const float* __restrict__ vit, const short* __restrict__ wfrag,
    const float* __restrict__ bias, short* __restrict__ feats)
{
    __shared__ float lds[KSTEP][PIXB];       // 16 KB

    const int bid  = blockIdx.x;             // 0..1535
    const int bv   = bid >> 5;               // 0..47
    const int pix0 = (bid & 31) * PIXB;

    const int tid  = threadIdx.x;
    const int wave = tid >> 6;               // 0..3
    const int l    = tid & 63;
    const int col  = l & 15;                 // pixel-in-tile / o-in-tile
    const int g    = l >> 4;                 // k-group
    const int lhalf = l >> 5;                // which k-row inside a DMA inst
    const int lq    = l & 31;                // 16B chunk within the row
    const int srcq  = (lq - 2 * wave) & 31;  // rotated source chunk

    const float* vbase = vit + (size_t)bv * CIN * HW + pix0;
    const short8v* wf  = reinterpret_cast<const short8v*>(wfrag);

    // Reader columns (rotation applied): row 8g+i holds global pixel P at
    // LDS col (P + 8g) & 127.
    const int rc0 = (wave * 32 + col + 8 * g) & 127;
    const int rc1 = (wave * 32 + col + 16 + 8 * g) & 127;

    f32x4 acc00 = {0.f, 0.f, 0.f, 0.f};
    f32x4 acc01 = {0.f, 0.f, 0.f, 0.f};
    f32x4 acc10 = {0.f, 0.f, 0.f, 0.f};
    f32x4 acc11 = {0.f, 0.f, 0.f, 0.f};

    // Prologue: DMA step 0.
#pragma unroll
    for (int i = 0; i < 4; ++i) {
        const int row = 8 * wave + 2 * i;
        load_lds16(vbase + (size_t)(row + lhalf) * HW + srcq * 4, &lds[row][0]);
    }

#pragma unroll
    for (int s = 0; s < KSTEPS; ++s) {
        __syncthreads();                     // vmcnt(0): DMA(s) landed

        float fr0[8], fr1[8];
#pragma unroll
        for (int i = 0; i < 8; ++i) {
            fr0[i] = lds[8 * g + i][rc0];
            fr1[i] = lds[8 * g + i][rc1];
        }
        __syncthreads();                     // reads done; LDS reusable

        if (s + 1 < KSTEPS) {
#pragma unroll
            for (int i = 0; i < 4; ++i) {
                const int row = 8 * wave + 2 * i;
                load_lds16(vbase + (size_t)((s + 1) * KSTEP + row + lhalf) * HW
                               + srcq * 4,
                           &lds[row][0]);
            }
        }

        short8v bfr0, bfr1;
#pragma unroll
        for (int i = 0; i < 8; ++i) {
            bfr0[i] = bf16b(fr0[i]);
            bfr1[i] = bf16b(fr1[i]);
        }

        const short8v a0 = wf[(s * 4 + g) * 32 + col];        // o = col
        const short8v a1 = wf[(s * 4 + g) * 32 + 16 + col];   // o = 16 + col

        acc00 = __builtin_amdgcn_mfma_f32_16x16x32_bf16(a0, bfr0, acc00, 0, 0, 0);
        acc01 = __builtin_amdgcn_mfma_f32_16x16x32_bf16(a1, bfr0, acc01, 0, 0, 0);
        acc10 = __builtin_amdgcn_mfma_f32_16x16x32_bf16(a0, bfr1, acc10, 0, 0, 0);
        acc11 = __builtin_amdgcn_mfma_f32_16x16x32_bf16(a1, bfr1, acc11, 0, 0, 0);
    }

    // Store bf16: feats[bv][pix][o]; lane's 4 accum elems are o = 4g+r.
    const float4 b0 = *reinterpret_cast<const float4*>(bias + 4 * g);
    const float4 b1 = *reinterpret_cast<const float4*>(bias + 16 + 4 * g);
    short* dst0 = feats + ((size_t)bv * HW + pix0 + wave * 32 + col) * COUT;
    short* dst1 = dst0 + 16 * COUT;
    short4v o00, o01, o10, o11;
    o00[0] = bf16b(acc00[0] + b0.x); o00[1] = bf16b(acc00[1] + b0.y);
    o00[2] = bf16b(acc00[2] + b0.z); o00[3] = bf16b(acc00[3] + b0.w);
    o01[0] = bf16b(acc01[0] + b1.x); o01[1] = bf16b(acc01[1] + b1.y);
    o01[2] = bf16b(acc01[2] + b1.z); o01[3] = bf16b(acc01[3] + b1.w);
    o10[0] = bf16b(acc10[0] + b0.x); o10[1] = bf16b(acc10[1] + b0.y);
    o10[2] = bf16b(acc10[2] + b0.z); o10[3] = bf16b(acc10[3] + b0.w);
    o11[0] = bf16b(acc11[0] + b1.x); o11[1] = bf16b(acc11[1] + b1.y);
    o11[2] = bf16b(acc11[2] + b1.z); o11[3] = bf16b(acc11[3] + b1.w);
    *reinterpret_cast<short4v*>(dst0 + 4 * g) = o00;
    *reinterpret_cast<short4v*>(dst0 + 16 + 4 * g) = o01;
    *reinterpret_cast<short4v*>(dst1 + 4 * g) = o10;
    *reinterpret_cast<short4v*>(dst1 + 16 + 4 * g) = o11;
}

// Kernel 2: fuse, 4 lanes per voxel (R8 form; single fp64 reciprocal per
// view instead of two divides — form already validated in R5/R6).
__global__ __launch_bounds__(256) void mv_fuse_kernel(
    const unsigned short* __restrict__ feats, const float* __restrict__ proj,
    float* __restrict__ out)
{
    __shared__ double P[NV][12];

    const int tid = threadIdx.x;
    const unsigned gid = blockIdx.x * 256u + tid;
    const unsigned vox = gid >> 2;          // voxel id = b*NVOX + n
    const int r = tid & 3;                  // chunk index within group
    const int lane = tid & 63;
    const int b = vox >> 18;
    const int n = vox & (NVOX - 1);

    if (tid < NV * 12) {
        const int v = tid / 12, e = tid - v * 12;
        const int row = e >> 2;
        const float s = (row < 2) ? 0.25f : 1.0f;   // projection[:,:, :2,:]/STRIDE
        P[v][e] = (double)(proj[((b * NV + v) * 3 + row) * 4 + (e & 3)] * s);
    }
    __syncthreads();

    const int k = n & 63, j = (n >> 6) & 63, i = n >> 12;
    const double wx = (double)i * 0.04 - 1.28;
    const double wy = (double)j * 0.04 - 1.28;
    const double wz = (double)k * 0.04 - 1.28;

    // Phase 1: this lane's 3 views (v = 4s + r).
    int off[3];
    int cnt = 0;
    const int bbase = b * (NV * HW * 4);
#pragma unroll
    for (int s = 0; s < 3; ++s) {
        const double* p = P[4 * s + r];
        const double cz = p[8] * wx + p[9] * wy + p[10] * wz + p[11];
        const double cx = p[0] * wx + p[1] * wy + p[2] * wz + p[3];
        const double cy = p[4] * wx + p[5] * wy + p[6] * wz + p[7];
        const double rcz = 1.0 / cz;
        const double u = rint(cx * rcz);   // round-half-even == jnp.round
        const double t = rint(cy * rcz);
        const bool valid = (cz > 0.0) & (u >= 0.0) & (u <= 63.0) &
                           (t >= 0.0) & (t <= 63.0);
        const double uc = fmin(fmax(u, 0.0), 63.0);
        const double tc = fmin(fmax(t, 0.0), 63.0);
        const int pix = (int)uc + 64 * (int)tc;
        off[s] = valid ? (bbase + ((4 * s + r) * HW + pix) * 4) : ZROW_U4;
        cnt += valid ? 1 : 0;
    }
    cnt += __shfl_xor(cnt, 1);
    cnt += __shfl_xor(cnt, 2);              // group-total valid count

    // Phase 2: gather + accumulate (channels 8r..8r+7 in this lane).
    float acc[8];
#pragma unroll
    for (int q = 0; q < 8; ++q) acc[q] = 0.0f;

    const uint4* f4 = reinterpret_cast<const uint4*>(feats);
#pragma unroll
    for (int v = 0; v < NV; ++v) {
        const int src = (lane & ~3) | (v & 3);      // owner lane of view v
        const int ov = __shfl(off[v >> 2], src, 64);
        const uint4 u4 = f4[ov + r];
        acc[0] += __uint_as_float(u4.x << 16);
        acc[1] += __uint_as_float(u4.x & 0xffff0000u);
        acc[2] += __uint_as_float(u4.y << 16);
        acc[3] += __uint_as_float(u4.y & 0xffff0000u);
        acc[4] += __uint_as_float(u4.z << 16);
        acc[5] += __uint_as_float(u4.z & 0xffff0000u);
        acc[6] += __uint_as_float(u4.w << 16);
        acc[7] += __uint_as_float(u4.w & 0xffff0000u);
    }

    const float sc = (cnt > 0) ? (1.0f / (float)cnt) : 0.0f;
    float* ob = out + (size_t)b * COUT * NVOX + (size_t)(8 * r) * NVOX + n;
#pragma unroll
    for (int q = 0; q < 8; ++q)
        ob[(size_t)q * NVOX] = acc[q] * sc;
}

extern "C" void kernel_launch(void* const* d_in, const int* in_sizes, int n_in,
                              void* d_out, int out_size, void* d_ws, size_t ws_size,
                              hipStream_t stream) {
    const float* vit  = (const float*)d_in[0];  // (4,12,384,64,64)
    const float* w    = (const float*)d_in[1];  // (32,384)
    const float* bias = (const float*)d_in[2];  // (32,)
    const float* proj = (const float*)d_in[3];  // (4,12,3,4)
    float* out = (float*)d_out;                 // (4,32,64,64,64)

    short* wfrag = (short*)d_ws;                            // 24 KB
    short* feats = (short*)((char*)d_ws + 48 * 32 * 8 * 2); // bf16 12.6 MB + 64B zero row

    w_prep_kernel<<<7, 256, 0, stream>>>(w, wfrag, feats);

    mv_reduce_mfma_kernel<<<1536, 256, 0, stream>>>(vit, wfrag, bias, feats);

    mv_fuse_kernel<<<16384, 256, 0, stream>>>(
        (const unsigned short*)feats, proj, out);
}